// Round 8
// baseline (2089.096 us; speedup 1.0000x reference)
//
#include <hip/hip_runtime.h>
#include <hip/hip_bf16.h>

#define TT 128
#define DD 1024   // padded per-operand K
#define HH 1000
#define NBLK 250  // persistent blocks: 125 per layer

typedef float f32x4 __attribute__((ext_vector_type(4)));
typedef __bf16 bf16x8 __attribute__((ext_vector_type(8)));

__device__ __forceinline__ bf16x8 asbf(f32x4 v) { return __builtin_bit_cast(bf16x8, v); }

// cached 16B load (L1+L2): used for all A-feed reads; L2 broadcasts the shared
// A-panel to the ~31 blocks of each XCD (stale lines dropped by the per-phase
// acquire fence below).
__device__ __forceinline__ void ld_a(bf16x8* d, const char* p) {
    asm volatile("global_load_dwordx4 %0, %1, off" : "=v"(*d) : "v"(p));
}
// cache-bypass 16B store: sc0 sc1 -> write through to L3 (coherence point).
// h never becomes dirty in any L2, so no writeback is ever needed.
__device__ __forceinline__ void st_byp(char* p, bf16x8 v) {
    asm volatile("global_store_dwordx4 %0, %1, off sc0 sc1" :: "v"(p), "v"(v) : "memory");
}

// ---------------------------------------------------------------------------
__global__ void zero_ws(unsigned int* __restrict__ p, int nwords) {
    int i = blockIdx.x * blockDim.x + threadIdx.x;
    if (i < nwords) p[i] = 0u;
}

// ---------------------------------------------------------------------------
// split x into bf16 hi/lo in MFMA A-fragment order (verified):
// unit gid = ((t*32 + ks)*4 + mt)*64 + lane ; elem j = x[mt*16+(lane&15)][t][ks*32+(lane>>4)*8+j]
__global__ void split_x(const float* __restrict__ x, __bf16* __restrict__ xfh,
                        __bf16* __restrict__ xfl) {
    int gid = blockIdx.x * 256 + threadIdx.x;     // 1,048,576 units
    int lane = gid & 63;
    int mt = (gid >> 6) & 3;
    int ks = (gid >> 8) & 31;
    int t  = gid >> 13;
    int row = mt * 16 + (lane & 15);
    int k0  = ks * 32 + (lane >> 4) * 8;
    const float* sp = x + ((size_t)row * TT + t) * 1024 + k0;
    float4 v0 = *(const float4*)sp;
    float4 v1 = *(const float4*)(sp + 4);
    float f[8] = {v0.x, v0.y, v0.z, v0.w, v1.x, v1.y, v1.z, v1.w};
    bf16x8 hv, lv;
#pragma unroll
    for (int j = 0; j < 8; ++j) {
        __bf16 h = (__bf16)f[j];
        hv[j] = h;
        lv[j] = (__bf16)(f[j] - (float)h);
    }
    ((bf16x8*)xfh)[gid] = hv;
    ((bf16x8*)xfl)[gid] = lv;
}

// ---------------------------------------------------------------------------
// Pack W/U into MFMA-B-fragment order via LDS tile (verified layout):
// unit = (nt*256 + kb)*16 + col; col' = 4*cell + gate; kb<128 = W, kb>=128 = U.
__global__ __launch_bounds__(256) void pack_w2(
    const float* __restrict__ W1, const float* __restrict__ U1,
    const float* __restrict__ W2, const float* __restrict__ U2,
    __bf16* __restrict__ w1h, __bf16* __restrict__ w1l,
    __bf16* __restrict__ w2h, __bf16* __restrict__ w2l)
{
    int nt = blockIdx.x;          // 0..249
    int layer = blockIdx.y;       // 0..1
    const float* R1 = layer ? W2 : W1;
    const float* R2 = layer ? U2 : U1;
    int k1v = layer ? HH : 1024;
    __bf16* dh = layer ? w2h : w1h;
    __bf16* dl = layer ? w2l : w1l;
    int tid = threadIdx.x;

    __shared__ float lt[64][21];

    int kk = tid >> 2, g = tid & 3;           // load role: 64 k rows x 4 gates
    for (int c = 0; c < 32; ++c) {            // 64 k per iter
        int k = c * 64 + kk;
        float4 v = {0.f, 0.f, 0.f, 0.f};
        if (k < 1024) {
            if (k < k1v) v = *(const float4*)(R1 + (size_t)k * 4000 + g * 1000 + nt * 4);
        } else {
            int k2 = k - 1024;
            if (k2 < HH) v = *(const float4*)(R2 + (size_t)k2 * 4000 + g * 1000 + nt * 4);
        }
        lt[kk][g * 4 + 0] = v.x; lt[kk][g * 4 + 1] = v.y;
        lt[kk][g * 4 + 2] = v.z; lt[kk][g * 4 + 3] = v.w;
        __syncthreads();
        if (tid < 128) {
            int kbl = tid >> 4, col = tid & 15;
            int li = (col & 3) * 4 + (col >> 2);   // gate*4 + cell_local
            bf16x8 hv, lv;
#pragma unroll
            for (int j = 0; j < 8; ++j) {
                float f = lt[kbl * 8 + j][li];
                __bf16 h = (__bf16)f;
                hv[j] = h;
                lv[j] = (__bf16)(f - (float)h);
            }
            size_t unit = ((size_t)nt * 256 + c * 8 + kbl) * 16 + col;
            ((bf16x8*)dh)[unit] = hv;
            ((bf16x8*)dl)[unit] = lv;
        }
        __syncthreads();
    }
}

// ---------------------------------------------------------------------------
// Persistent LSTM. Weights pinned in AGPRs ("+a", verified round 6).
// h exchange: sc0sc1 stores -> L3; cached A-loads; ONE acquire fence
// (buffer_inv sc1) per block per phase after the relaxed flag barrier.
__global__ __launch_bounds__(256, 1) void lstm_persist(
    const __bf16* __restrict__ xfh, const __bf16* __restrict__ xfl,
    const __bf16* __restrict__ w1h, const __bf16* __restrict__ w1l,
    const __bf16* __restrict__ w2h, const __bf16* __restrict__ w2l,
    const float* __restrict__ b1, const float* __restrict__ b2,
    __bf16* hbuf, unsigned int* bar, unsigned int* flag)
{
    const int bid = blockIdx.x;
    const int layer = bid >= 125;
    const int nb = layer ? bid - 125 : bid;
    const int tid = threadIdx.x;
    const int lane = tid & 63, w = tid >> 6;
    const int op = w >> 1, kh = w & 1;
    const int ln = lane & 15, kg = lane >> 4;

    const char* h1h[2] = { (const char*)(hbuf + 0 * 65536), (const char*)(hbuf + 1 * 65536) };
    const char* h1l[2] = { (const char*)(hbuf + 2 * 65536), (const char*)(hbuf + 3 * 65536) };
    const char* h2h[2] = { (const char*)(hbuf + 4 * 65536), (const char*)(hbuf + 5 * 65536) };
    const char* h2l[2] = { (const char*)(hbuf + 6 * 65536), (const char*)(hbuf + 7 * 65536) };

    // ---- preload weight panel into AGPRs (verified pin, round 6) ----
    const f32x4* wfh = (const f32x4*)(layer ? w2h : w1h);
    const f32x4* wfl = (const f32x4*)(layer ? w2l : w1l);
    f32x4 WH[32], WL[32];
#pragma unroll
    for (int nt2 = 0; nt2 < 2; ++nt2)
#pragma unroll
        for (int ks = 0; ks < 16; ++ks) {
            int kb = op * 128 + kh * 64 + ks * 4 + kg;
            size_t unit = ((size_t)(nb * 2 + nt2) * 256 + kb) * 16 + ln;
            WH[nt2 * 16 + ks] = wfh[unit];
            WL[nt2 * 16 + ks] = wfl[unit];
        }
#define PIN8(p0,p1,p2,p3,p4,p5,p6,p7) \
    asm volatile("" : "+a"(p0),"+a"(p1),"+a"(p2),"+a"(p3),"+a"(p4),"+a"(p5),"+a"(p6),"+a"(p7))
    PIN8(WH[0],WH[1],WH[2],WH[3],WH[4],WH[5],WH[6],WH[7]);
    PIN8(WH[8],WH[9],WH[10],WH[11],WH[12],WH[13],WH[14],WH[15]);
    PIN8(WH[16],WH[17],WH[18],WH[19],WH[20],WH[21],WH[22],WH[23]);
    PIN8(WH[24],WH[25],WH[26],WH[27],WH[28],WH[29],WH[30],WH[31]);
    PIN8(WL[0],WL[1],WL[2],WL[3],WL[4],WL[5],WL[6],WL[7]);
    PIN8(WL[8],WL[9],WL[10],WL[11],WL[12],WL[13],WL[14],WL[15]);
    PIN8(WL[16],WL[17],WL[18],WL[19],WL[20],WL[21],WL[22],WL[23]);
    PIN8(WL[24],WL[25],WL[26],WL[27],WL[28],WL[29],WL[30],WL[31]);
#undef PIN8

    // ---- per-thread bias + register-resident c state ----
    const float* bias = layer ? b2 : b1;
    float bias_q[2][4];
#pragma unroll
    for (int q = 0; q < 2; ++q) {
        int task = tid * 2 + q;
        int n = nb * 8 + (task & 7);
#pragma unroll
        for (int g = 0; g < 4; ++g) bias_q[q][g] = bias[(size_t)g * HH + n];
    }
    float creg[2] = {0.f, 0.f};

    __shared__ float zs[2][64][34];   // pad 34 -> exact 2-way (free)
    __shared__ float hs[64][9];

#pragma unroll 1
    for (int t = 0; t <= TT; ++t) {
        const bool active = layer ? (t >= 1) : (t <= TT - 1);
        if (active) {
            const char *pAh, *pAl;
            char *poh, *pol;
            if (layer == 0) {
                if (op == 0) { pAh = (const char*)xfh + (size_t)t * 131072;
                               pAl = (const char*)xfl + (size_t)t * 131072; }
                else         { pAh = h1h[(t + 1) & 1]; pAl = h1l[(t + 1) & 1]; }
                poh = (char*)h1h[t & 1]; pol = (char*)h1l[t & 1];
            } else {
                if (op == 0) { pAh = h1h[(t + 1) & 1]; pAl = h1l[(t + 1) & 1]; }
                else         { pAh = h2h[t & 1];       pAl = h2l[t & 1]; }
                poh = (char*)h2h[(t + 1) & 1]; pol = (char*)h2l[(t + 1) & 1];
            }
            pAh += ((size_t)kh * 4096 + lane) * 16;
            pAl += ((size_t)kh * 4096 + lane) * 16;

            f32x4 acc[2][4];
#pragma unroll
            for (int n2 = 0; n2 < 2; ++n2)
#pragma unroll
                for (int mt = 0; mt < 4; ++mt) acc[n2][mt] = (f32x4){0.f, 0.f, 0.f, 0.f};

            bf16x8 rh[4][4], rl[4][4];
#define LDB(s, k) do { _Pragma("unroll") \
    for (int mt = 0; mt < 4; ++mt) { \
        ld_a(&rh[s][mt], pAh + (size_t)((k) * 256 + mt * 64) * 16); \
        ld_a(&rl[s][mt], pAl + (size_t)((k) * 256 + mt * 64) * 16); \
    } } while (0)
#define CPK(k, s) do { _Pragma("unroll") \
    for (int n2 = 0; n2 < 2; ++n2) { \
        bf16x8 wh_ = asbf(WH[n2 * 16 + (k)]); \
        bf16x8 wl_ = asbf(WL[n2 * 16 + (k)]); \
        _Pragma("unroll") \
        for (int mt = 0; mt < 4; ++mt) { \
            acc[n2][mt] = __builtin_amdgcn_mfma_f32_16x16x32_bf16(rh[s][mt], wh_, acc[n2][mt], 0, 0, 0); \
            acc[n2][mt] = __builtin_amdgcn_mfma_f32_16x16x32_bf16(rh[s][mt], wl_, acc[n2][mt], 0, 0, 0); \
            acc[n2][mt] = __builtin_amdgcn_mfma_f32_16x16x32_bf16(rl[s][mt], wh_, acc[n2][mt], 0, 0, 0); \
        } } } while (0)

            LDB(0, 0); LDB(1, 1); LDB(2, 2); LDB(3, 3);
#pragma unroll
            for (int ks = 0; ks < 16; ++ks) {
                // counted vmcnt: slot ks complete, up to 3 newer slots in flight
                if (ks <= 12)      asm volatile("s_waitcnt vmcnt(24)" ::: "memory");
                else if (ks == 13) asm volatile("s_waitcnt vmcnt(16)" ::: "memory");
                else if (ks == 14) asm volatile("s_waitcnt vmcnt(8)"  ::: "memory");
                else               asm volatile("s_waitcnt vmcnt(0)"  ::: "memory");
                __builtin_amdgcn_sched_barrier(0);
                CPK(ks, ks & 3);
                if (ks < 12) LDB(ks & 3, ks + 4);
            }
#undef LDB
#undef CPK

            // ---- two-stage partial-z reduction: kh0 writes, kh1 adds ----
            if (kh == 0) {
#pragma unroll
                for (int n2 = 0; n2 < 2; ++n2)
#pragma unroll
                    for (int mt = 0; mt < 4; ++mt)
#pragma unroll
                        for (int r = 0; r < 4; ++r)
                            zs[op][mt * 16 + kg * 4 + r][n2 * 16 + ln] = acc[n2][mt][r];
            }
            __syncthreads();
            if (kh == 1) {
#pragma unroll
                for (int n2 = 0; n2 < 2; ++n2)
#pragma unroll
                    for (int mt = 0; mt < 4; ++mt)
#pragma unroll
                        for (int r = 0; r < 4; ++r)
                            zs[op][mt * 16 + kg * 4 + r][n2 * 16 + ln] += acc[n2][mt][r];
            }
            __syncthreads();

            // ---- fused gates: 512 (b,cell) tasks, 2/thread; c in registers ----
#pragma unroll
            for (int q = 0; q < 2; ++q) {
                int task = tid * 2 + q;
                int b = task >> 3, cl = task & 7;
                float zg[4];
#pragma unroll
                for (int g = 0; g < 4; ++g)
                    zg[g] = zs[0][b][cl * 4 + g] + zs[1][b][cl * 4 + g] + bias_q[q][g];
                float ig = 1.f / (1.f + __expf(-zg[0]));
                float fg = 1.f / (1.f + __expf(-zg[1]));
                float gg = 1.f - 2.f / (__expf(2.f * zg[2]) + 1.f);
                float og = 1.f / (1.f + __expf(-zg[3]));
                float cn = fg * creg[q] + ig * gg;
                creg[q] = cn;
                hs[b][cl] = og * (1.f - 2.f / (__expf(2.f * cn) + 1.f));
            }
            __syncthreads();

            // ---- write h in fragment order via bypass stores (-> L3) ----
            if (tid < 64) {
                int b = tid;
                int mt = b >> 4, lnn = b & 15;
                int ksx = nb >> 2, kgg = nb & 3;
                bf16x8 hv, lv;
#pragma unroll
                for (int j = 0; j < 8; ++j) {
                    float v = hs[b][j];
                    __bf16 h = (__bf16)v;
                    hv[j] = h;
                    lv[j] = (__bf16)(v - (float)h);
                }
                size_t boff = (((size_t)ksx * 4 + mt) * 64 + kgg * 16 + lnn) * 16;
                st_byp(poh + boff, hv);
                st_byp(pol + boff, lv);
            }
        }

        // ---- relaxed grid barrier + single acquire fence per phase ----
        if (t < TT) {
            asm volatile("s_waitcnt vmcnt(0)" ::: "memory");  // h stores at L3
            __syncthreads();
            if (tid == 0) {
                unsigned int target = (unsigned int)(t + 1) * NBLK;
                unsigned int old = __hip_atomic_fetch_add(bar, 1u, __ATOMIC_RELAXED,
                                                          __HIP_MEMORY_SCOPE_AGENT);
                if (old == target - 1u) {
                    __hip_atomic_store(flag, target, __ATOMIC_RELAXED,
                                       __HIP_MEMORY_SCOPE_AGENT);
                } else {
                    while (__hip_atomic_load(flag, __ATOMIC_RELAXED,
                                             __HIP_MEMORY_SCOPE_AGENT) < target)
                        __builtin_amdgcn_s_sleep(1);
                }
                // drop stale h lines from this CU's L1 + this XCD's L2
                __builtin_amdgcn_fence(__ATOMIC_ACQUIRE, "agent");
            }
            __syncthreads();
        }
    }
}

// ---------------------------------------------------------------------------
// out[b][o] = bo[o] + sum_n h2[b][n] * Wo[n][o] ; h2 in fragment order
__global__ void out_proj(const __bf16* __restrict__ h2h, const __bf16* __restrict__ h2l,
                         const float* __restrict__ Wo, const float* __restrict__ bo,
                         float* __restrict__ out)
{
    int b = blockIdx.x, tid = threadIdx.x;
    int mt = b >> 4, ln = b & 15;
    float acc[6] = {0, 0, 0, 0, 0, 0};
    for (int n = tid; n < HH; n += 256) {
        int ks = n >> 5, kg = (n >> 3) & 3, j = n & 7;
        size_t idx = (((size_t)ks * 4 + mt) * 64 + kg * 16 + ln) * 8 + j;
        float h = (float)h2h[idx] + (float)h2l[idx];
#pragma unroll
        for (int o = 0; o < 6; ++o) acc[o] += h * Wo[n * 6 + o];
    }
#pragma unroll
    for (int o = 0; o < 6; ++o)
        for (int off = 32; off; off >>= 1) acc[o] += __shfl_down(acc[o], off, 64);
    __shared__ float red[4][6];
    int lane = tid & 63, wv = tid >> 6;
    if (lane == 0) {
#pragma unroll
        for (int o = 0; o < 6; ++o) red[wv][o] = acc[o];
    }
    __syncthreads();
    if (tid < 6) {
        float s = bo[tid];
#pragma unroll
        for (int w = 0; w < 4; ++w) s += red[w][tid];
        out[b * 6 + tid] = s;
    }
}

// ---------------------------------------------------------------------------
extern "C" void kernel_launch(void* const* d_in, const int* in_sizes, int n_in,
                              void* d_out, int out_size, void* d_ws, size_t ws_size,
                              hipStream_t stream) {
    const float* x  = (const float*)d_in[0];
    const float* W1 = (const float*)d_in[1];
    const float* U1 = (const float*)d_in[2];
    const float* b1 = (const float*)d_in[3];
    const float* W2 = (const float*)d_in[4];
    const float* U2 = (const float*)d_in[5];
    const float* b2 = (const float*)d_in[6];
    const float* Wo = (const float*)d_in[7];
    const float* bo = (const float*)d_in[8];
    float* out = (float*)d_out;

    // ws carve: zeroed region first [hbuf 1MB, bar/flag 256B]
    char* p = (char*)d_ws;
    __bf16* hbuf = (__bf16*)p; p += (size_t)8 * 65536 * 2;     // 8 x frag[64x1024]
    unsigned int* bar  = (unsigned int*)p;
    unsigned int* flag = (unsigned int*)(p + 64); p += 256;
    __bf16* xfh = (__bf16*)p; p += (size_t)8388608 * 2;
    __bf16* xfl = (__bf16*)p; p += (size_t)8388608 * 2;
    __bf16* w1h = (__bf16*)p; p += (size_t)8192000 * 2;
    __bf16* w1l = (__bf16*)p; p += (size_t)8192000 * 2;
    __bf16* w2h = (__bf16*)p; p += (size_t)8192000 * 2;
    __bf16* w2l = (__bf16*)p; p += (size_t)8192000 * 2;

    // ---- preprocessing ----
    zero_ws<<<1025, 256, 0, stream>>>((unsigned int*)d_ws, 262208);
    split_x<<<4096, 256, 0, stream>>>(x, xfh, xfl);
    pack_w2<<<dim3(250, 2), 256, 0, stream>>>(W1, U1, W2, U2, w1h, w1l, w2h, w2l);

    // ---- persistent pipelined recurrence (all 129 phases) ----
    lstm_persist<<<NBLK, 256, 0, stream>>>(xfh, xfl, w1h, w1l, w2h, w2l,
                                           b1, b2, hbuf, bar, flag);

    // h2(127) is in buffer index 1
    out_proj<<<64, 256, 0, stream>>>(hbuf + 5 * 65536, hbuf + 7 * 65536, Wo, bo, out);
}

// Round 9
// 1954.363 us; speedup vs baseline: 1.0689x; 1.0689x over previous
//
#include <hip/hip_runtime.h>
#include <hip/hip_bf16.h>

#define TT 128
#define DD 1024   // padded per-operand K
#define HH 1000
#define NBLK 250  // persistent blocks: 125 per layer

typedef float f32x4 __attribute__((ext_vector_type(4)));
typedef __bf16 bf16x8 __attribute__((ext_vector_type(8)));

__device__ __forceinline__ bf16x8 asbf(f32x4 v) { return __builtin_bit_cast(bf16x8, v); }

// A-feed load: sc0 = L1-bypass, L2-CACHEABLE. First block on an XCD fills L2
// from L3; the other ~30 blocks hit L2. Staleness handled by one
// buffer_inv per XCD per phase (leader block below).
__device__ __forceinline__ void ld_a(bf16x8* d, const char* p) {
    asm volatile("global_load_dwordx4 %0, %1, off sc0" : "=v"(*d) : "v"(p));
}
// h store: sc0 sc1 = write-through to L3 (coherence point). h lines are never
// dirty in any L2, so the per-phase clean invalidate can't lose data.
__device__ __forceinline__ void st_byp(char* p, bf16x8 v) {
    asm volatile("global_store_dwordx4 %0, %1, off sc0 sc1" :: "v"(p), "v"(v) : "memory");
}

// ---------------------------------------------------------------------------
__global__ void zero_ws(unsigned int* __restrict__ p, int nwords) {
    int i = blockIdx.x * blockDim.x + threadIdx.x;
    if (i < nwords) p[i] = 0u;
}

// ---------------------------------------------------------------------------
// split x into bf16 hi/lo in MFMA A-fragment order (verified):
// unit gid = ((t*32 + ks)*4 + mt)*64 + lane ; elem j = x[mt*16+(lane&15)][t][ks*32+(lane>>4)*8+j]
__global__ void split_x(const float* __restrict__ x, __bf16* __restrict__ xfh,
                        __bf16* __restrict__ xfl) {
    int gid = blockIdx.x * 256 + threadIdx.x;     // 1,048,576 units
    int lane = gid & 63;
    int mt = (gid >> 6) & 3;
    int ks = (gid >> 8) & 31;
    int t  = gid >> 13;
    int row = mt * 16 + (lane & 15);
    int k0  = ks * 32 + (lane >> 4) * 8;
    const float* sp = x + ((size_t)row * TT + t) * 1024 + k0;
    float4 v0 = *(const float4*)sp;
    float4 v1 = *(const float4*)(sp + 4);
    float f[8] = {v0.x, v0.y, v0.z, v0.w, v1.x, v1.y, v1.z, v1.w};
    bf16x8 hv, lv;
#pragma unroll
    for (int j = 0; j < 8; ++j) {
        __bf16 h = (__bf16)f[j];
        hv[j] = h;
        lv[j] = (__bf16)(f[j] - (float)h);
    }
    ((bf16x8*)xfh)[gid] = hv;
    ((bf16x8*)xfl)[gid] = lv;
}

// ---------------------------------------------------------------------------
// Pack W/U into MFMA-B-fragment order via LDS tile (verified layout):
// unit = (nt*256 + kb)*16 + col; col' = 4*cell + gate; kb<128 = W, kb>=128 = U.
__global__ __launch_bounds__(256) void pack_w2(
    const float* __restrict__ W1, const float* __restrict__ U1,
    const float* __restrict__ W2, const float* __restrict__ U2,
    __bf16* __restrict__ w1h, __bf16* __restrict__ w1l,
    __bf16* __restrict__ w2h, __bf16* __restrict__ w2l)
{
    int nt = blockIdx.x;          // 0..249
    int layer = blockIdx.y;       // 0..1
    const float* R1 = layer ? W2 : W1;
    const float* R2 = layer ? U2 : U1;
    int k1v = layer ? HH : 1024;
    __bf16* dh = layer ? w2h : w1h;
    __bf16* dl = layer ? w2l : w1l;
    int tid = threadIdx.x;

    __shared__ float lt[64][21];

    int kk = tid >> 2, g = tid & 3;           // load role: 64 k rows x 4 gates
    for (int c = 0; c < 32; ++c) {            // 64 k per iter
        int k = c * 64 + kk;
        float4 v = {0.f, 0.f, 0.f, 0.f};
        if (k < 1024) {
            if (k < k1v) v = *(const float4*)(R1 + (size_t)k * 4000 + g * 1000 + nt * 4);
        } else {
            int k2 = k - 1024;
            if (k2 < HH) v = *(const float4*)(R2 + (size_t)k2 * 4000 + g * 1000 + nt * 4);
        }
        lt[kk][g * 4 + 0] = v.x; lt[kk][g * 4 + 1] = v.y;
        lt[kk][g * 4 + 2] = v.z; lt[kk][g * 4 + 3] = v.w;
        __syncthreads();
        if (tid < 128) {
            int kbl = tid >> 4, col = tid & 15;
            int li = (col & 3) * 4 + (col >> 2);   // gate*4 + cell_local
            bf16x8 hv, lv;
#pragma unroll
            for (int j = 0; j < 8; ++j) {
                float f = lt[kbl * 8 + j][li];
                __bf16 h = (__bf16)f;
                hv[j] = h;
                lv[j] = (__bf16)(f - (float)h);
            }
            size_t unit = ((size_t)nt * 256 + c * 8 + kbl) * 16 + col;
            ((bf16x8*)dh)[unit] = hv;
            ((bf16x8*)dl)[unit] = lv;
        }
        __syncthreads();
    }
}

// ---------------------------------------------------------------------------
// Persistent LSTM. Weights pinned in AGPRs ("+a", verified round 6).
// h exchange: sc0sc1 stores -> L3. A-feed: sc0 loads (L2-cached broadcast).
// Coherence: ONE buffer_inv (acquire fence) per XCD per phase, issued by a
// per-XCD leader elected at start via HW_REG_XCC_ID; other blocks on the XCD
// poll xcd_done (relaxed agent atomics, L3-served, no inv).
__global__ __launch_bounds__(256, 1) void lstm_persist(
    const __bf16* __restrict__ xfh, const __bf16* __restrict__ xfl,
    const __bf16* __restrict__ w1h, const __bf16* __restrict__ w1l,
    const __bf16* __restrict__ w2h, const __bf16* __restrict__ w2l,
    const float* __restrict__ b1, const float* __restrict__ b2,
    __bf16* hbuf, unsigned int* bar, unsigned int* flag,
    unsigned int* xcdm, unsigned int* xcdd)
{
    const int bid = blockIdx.x;
    const int layer = bid >= 125;
    const int nb = layer ? bid - 125 : bid;
    const int tid = threadIdx.x;
    const int lane = tid & 63, w = tid >> 6;
    const int op = w >> 1, kh = w & 1;
    const int ln = lane & 15, kg = lane >> 4;

    const char* h1h[2] = { (const char*)(hbuf + 0 * 65536), (const char*)(hbuf + 1 * 65536) };
    const char* h1l[2] = { (const char*)(hbuf + 2 * 65536), (const char*)(hbuf + 3 * 65536) };
    const char* h2h[2] = { (const char*)(hbuf + 4 * 65536), (const char*)(hbuf + 5 * 65536) };
    const char* h2l[2] = { (const char*)(hbuf + 6 * 65536), (const char*)(hbuf + 7 * 65536) };

    // ---- per-XCD leader election (once): leader = first arriver on its XCD ----
    __shared__ unsigned s_ldr;    // (xcd << 8) | is_leader
    if (tid == 0) {
        unsigned x;
        asm volatile("s_getreg_b32 %0, hwreg(HW_REG_XCC_ID)" : "=s"(x));
        x &= 7u;
        unsigned old = __hip_atomic_fetch_add(&xcdm[x], 1u, __ATOMIC_RELAXED,
                                              __HIP_MEMORY_SCOPE_AGENT);
        s_ldr = (x << 8) | (old == 0u ? 1u : 0u);
    }

    // ---- preload weight panel into AGPRs (verified pin, round 6) ----
    const f32x4* wfh = (const f32x4*)(layer ? w2h : w1h);
    const f32x4* wfl = (const f32x4*)(layer ? w2l : w1l);
    f32x4 WH[32], WL[32];
#pragma unroll
    for (int nt2 = 0; nt2 < 2; ++nt2)
#pragma unroll
        for (int ks = 0; ks < 16; ++ks) {
            int kb = op * 128 + kh * 64 + ks * 4 + kg;
            size_t unit = ((size_t)(nb * 2 + nt2) * 256 + kb) * 16 + ln;
            WH[nt2 * 16 + ks] = wfh[unit];
            WL[nt2 * 16 + ks] = wfl[unit];
        }
#define PIN8(p0,p1,p2,p3,p4,p5,p6,p7) \
    asm volatile("" : "+a"(p0),"+a"(p1),"+a"(p2),"+a"(p3),"+a"(p4),"+a"(p5),"+a"(p6),"+a"(p7))
    PIN8(WH[0],WH[1],WH[2],WH[3],WH[4],WH[5],WH[6],WH[7]);
    PIN8(WH[8],WH[9],WH[10],WH[11],WH[12],WH[13],WH[14],WH[15]);
    PIN8(WH[16],WH[17],WH[18],WH[19],WH[20],WH[21],WH[22],WH[23]);
    PIN8(WH[24],WH[25],WH[26],WH[27],WH[28],WH[29],WH[30],WH[31]);
    PIN8(WL[0],WL[1],WL[2],WL[3],WL[4],WL[5],WL[6],WL[7]);
    PIN8(WL[8],WL[9],WL[10],WL[11],WL[12],WL[13],WL[14],WL[15]);
    PIN8(WL[16],WL[17],WL[18],WL[19],WL[20],WL[21],WL[22],WL[23]);
    PIN8(WL[24],WL[25],WL[26],WL[27],WL[28],WL[29],WL[30],WL[31]);
#undef PIN8

    // ---- per-thread bias + register-resident c state ----
    const float* bias = layer ? b2 : b1;
    float bias_q[2][4];
#pragma unroll
    for (int q = 0; q < 2; ++q) {
        int task = tid * 2 + q;
        int n = nb * 8 + (task & 7);
#pragma unroll
        for (int g = 0; g < 4; ++g) bias_q[q][g] = bias[(size_t)g * HH + n];
    }
    float creg[2] = {0.f, 0.f};

    __shared__ float zs[2][64][34];   // pad 34 -> exact 2-way (free)
    __shared__ float hs[64][9];
    __syncthreads();                  // s_ldr visible

#pragma unroll 1
    for (int t = 0; t <= TT; ++t) {
        const bool active = layer ? (t >= 1) : (t <= TT - 1);
        if (active) {
            const char *pAh, *pAl;
            char *poh, *pol;
            if (layer == 0) {
                if (op == 0) { pAh = (const char*)xfh + (size_t)t * 131072;
                               pAl = (const char*)xfl + (size_t)t * 131072; }
                else         { pAh = h1h[(t + 1) & 1]; pAl = h1l[(t + 1) & 1]; }
                poh = (char*)h1h[t & 1]; pol = (char*)h1l[t & 1];
            } else {
                if (op == 0) { pAh = h1h[(t + 1) & 1]; pAl = h1l[(t + 1) & 1]; }
                else         { pAh = h2h[t & 1];       pAl = h2l[t & 1]; }
                poh = (char*)h2h[(t + 1) & 1]; pol = (char*)h2l[(t + 1) & 1];
            }
            pAh += ((size_t)kh * 4096 + lane) * 16;
            pAl += ((size_t)kh * 4096 + lane) * 16;

            f32x4 acc[2][4];
#pragma unroll
            for (int n2 = 0; n2 < 2; ++n2)
#pragma unroll
                for (int mt = 0; mt < 4; ++mt) acc[n2][mt] = (f32x4){0.f, 0.f, 0.f, 0.f};

            bf16x8 rh[4][4], rl[4][4];
#define LDB(s, k) do { _Pragma("unroll") \
    for (int mt = 0; mt < 4; ++mt) { \
        ld_a(&rh[s][mt], pAh + (size_t)((k) * 256 + mt * 64) * 16); \
        ld_a(&rl[s][mt], pAl + (size_t)((k) * 256 + mt * 64) * 16); \
    } } while (0)
#define CPK(k, s) do { _Pragma("unroll") \
    for (int n2 = 0; n2 < 2; ++n2) { \
        bf16x8 wh_ = asbf(WH[n2 * 16 + (k)]); \
        bf16x8 wl_ = asbf(WL[n2 * 16 + (k)]); \
        _Pragma("unroll") \
        for (int mt = 0; mt < 4; ++mt) { \
            acc[n2][mt] = __builtin_amdgcn_mfma_f32_16x16x32_bf16(rh[s][mt], wh_, acc[n2][mt], 0, 0, 0); \
            acc[n2][mt] = __builtin_amdgcn_mfma_f32_16x16x32_bf16(rh[s][mt], wl_, acc[n2][mt], 0, 0, 0); \
            acc[n2][mt] = __builtin_amdgcn_mfma_f32_16x16x32_bf16(rl[s][mt], wh_, acc[n2][mt], 0, 0, 0); \
        } } } while (0)

            LDB(0, 0); LDB(1, 1); LDB(2, 2); LDB(3, 3);
#pragma unroll
            for (int ks = 0; ks < 16; ++ks) {
                // counted vmcnt: slot ks complete, up to 3 newer slots in flight
                if (ks <= 12)      asm volatile("s_waitcnt vmcnt(24)" ::: "memory");
                else if (ks == 13) asm volatile("s_waitcnt vmcnt(16)" ::: "memory");
                else if (ks == 14) asm volatile("s_waitcnt vmcnt(8)"  ::: "memory");
                else               asm volatile("s_waitcnt vmcnt(0)"  ::: "memory");
                __builtin_amdgcn_sched_barrier(0);
                CPK(ks, ks & 3);
                if (ks < 12) LDB(ks & 3, ks + 4);
            }
#undef LDB
#undef CPK

            // ---- two-stage partial-z reduction: kh0 writes, kh1 adds ----
            if (kh == 0) {
#pragma unroll
                for (int n2 = 0; n2 < 2; ++n2)
#pragma unroll
                    for (int mt = 0; mt < 4; ++mt)
#pragma unroll
                        for (int r = 0; r < 4; ++r)
                            zs[op][mt * 16 + kg * 4 + r][n2 * 16 + ln] = acc[n2][mt][r];
            }
            __syncthreads();
            if (kh == 1) {
#pragma unroll
                for (int n2 = 0; n2 < 2; ++n2)
#pragma unroll
                    for (int mt = 0; mt < 4; ++mt)
#pragma unroll
                        for (int r = 0; r < 4; ++r)
                            zs[op][mt * 16 + kg * 4 + r][n2 * 16 + ln] += acc[n2][mt][r];
            }
            __syncthreads();

            // ---- fused gates: 512 (b,cell) tasks, 2/thread; c in registers ----
#pragma unroll
            for (int q = 0; q < 2; ++q) {
                int task = tid * 2 + q;
                int b = task >> 3, cl = task & 7;
                float zg[4];
#pragma unroll
                for (int g = 0; g < 4; ++g)
                    zg[g] = zs[0][b][cl * 4 + g] + zs[1][b][cl * 4 + g] + bias_q[q][g];
                float ig = 1.f / (1.f + __expf(-zg[0]));
                float fg = 1.f / (1.f + __expf(-zg[1]));
                float gg = 1.f - 2.f / (__expf(2.f * zg[2]) + 1.f);
                float og = 1.f / (1.f + __expf(-zg[3]));
                float cn = fg * creg[q] + ig * gg;
                creg[q] = cn;
                hs[b][cl] = og * (1.f - 2.f / (__expf(2.f * cn) + 1.f));
            }
            __syncthreads();

            // ---- write h in fragment order via bypass stores (-> L3) ----
            if (tid < 64) {
                int b = tid;
                int mt = b >> 4, lnn = b & 15;
                int ksx = nb >> 2, kgg = nb & 3;
                bf16x8 hv, lv;
#pragma unroll
                for (int j = 0; j < 8; ++j) {
                    float v = hs[b][j];
                    __bf16 h = (__bf16)v;
                    hv[j] = h;
                    lv[j] = (__bf16)(v - (float)h);
                }
                size_t boff = (((size_t)ksx * 4 + mt) * 64 + kgg * 16 + lnn) * 16;
                st_byp(poh + boff, hv);
                st_byp(pol + boff, lv);
            }
        }

        // ---- relaxed global barrier, then ONE inv per XCD (leader) ----
        if (t < TT) {
            asm volatile("s_waitcnt vmcnt(0)" ::: "memory");  // h stores at L3
            __syncthreads();
            if (tid == 0) {
                unsigned target = (unsigned)(t + 1) * NBLK;
                unsigned old = __hip_atomic_fetch_add(bar, 1u, __ATOMIC_RELAXED,
                                                      __HIP_MEMORY_SCOPE_AGENT);
                if (old == target - 1u) {
                    __hip_atomic_store(flag, target, __ATOMIC_RELAXED,
                                       __HIP_MEMORY_SCOPE_AGENT);
                } else {
                    while (__hip_atomic_load(flag, __ATOMIC_RELAXED,
                                             __HIP_MEMORY_SCOPE_AGENT) < target)
                        __builtin_amdgcn_s_sleep(1);
                }
                unsigned info = s_ldr;
                unsigned* dptr = xcdd + (info >> 8) * 16;
                if (info & 1u) {
                    // drop stale clean h lines from this XCD's L2 (+ own L1)
                    __builtin_amdgcn_fence(__ATOMIC_ACQUIRE, "agent");
                    asm volatile("s_waitcnt vmcnt(0)" ::: "memory");
                    __hip_atomic_store(dptr, (unsigned)(t + 1), __ATOMIC_RELAXED,
                                       __HIP_MEMORY_SCOPE_AGENT);
                } else {
                    while (__hip_atomic_load(dptr, __ATOMIC_RELAXED,
                                             __HIP_MEMORY_SCOPE_AGENT) < (unsigned)(t + 1))
                        __builtin_amdgcn_s_sleep(1);
                    asm volatile("" ::: "memory");
                }
            }
            __syncthreads();
        }
    }
}

// ---------------------------------------------------------------------------
// out[b][o] = bo[o] + sum_n h2[b][n] * Wo[n][o] ; h2 in fragment order
__global__ void out_proj(const __bf16* __restrict__ h2h, const __bf16* __restrict__ h2l,
                         const float* __restrict__ Wo, const float* __restrict__ bo,
                         float* __restrict__ out)
{
    int b = blockIdx.x, tid = threadIdx.x;
    int mt = b >> 4, ln = b & 15;
    float acc[6] = {0, 0, 0, 0, 0, 0};
    for (int n = tid; n < HH; n += 256) {
        int ks = n >> 5, kg = (n >> 3) & 3, j = n & 7;
        size_t idx = (((size_t)ks * 4 + mt) * 64 + kg * 16 + ln) * 8 + j;
        float h = (float)h2h[idx] + (float)h2l[idx];
#pragma unroll
        for (int o = 0; o < 6; ++o) acc[o] += h * Wo[n * 6 + o];
    }
#pragma unroll
    for (int o = 0; o < 6; ++o)
        for (int off = 32; off; off >>= 1) acc[o] += __shfl_down(acc[o], off, 64);
    __shared__ float red[4][6];
    int lane = tid & 63, wv = tid >> 6;
    if (lane == 0) {
#pragma unroll
        for (int o = 0; o < 6; ++o) red[wv][o] = acc[o];
    }
    __syncthreads();
    if (tid < 6) {
        float s = bo[tid];
#pragma unroll
        for (int w = 0; w < 4; ++w) s += red[w][tid];
        out[b * 6 + tid] = s;
    }
}

// ---------------------------------------------------------------------------
extern "C" void kernel_launch(void* const* d_in, const int* in_sizes, int n_in,
                              void* d_out, int out_size, void* d_ws, size_t ws_size,
                              hipStream_t stream) {
    const float* x  = (const float*)d_in[0];
    const float* W1 = (const float*)d_in[1];
    const float* U1 = (const float*)d_in[2];
    const float* b1 = (const float*)d_in[3];
    const float* W2 = (const float*)d_in[4];
    const float* U2 = (const float*)d_in[5];
    const float* b2 = (const float*)d_in[6];
    const float* Wo = (const float*)d_in[7];
    const float* bo = (const float*)d_in[8];
    float* out = (float*)d_out;

    // ws carve: zeroed region first [hbuf 1MB, ctrl 2KB]
    char* p = (char*)d_ws;
    __bf16* hbuf = (__bf16*)p; p += (size_t)8 * 65536 * 2;     // 8 x frag[64x1024]
    unsigned int* bar  = (unsigned int*)p;           // +0
    unsigned int* flag = (unsigned int*)(p + 64);    // +64B
    unsigned int* xcdm = (unsigned int*)(p + 128);   // 8 uints
    unsigned int* xcdd = (unsigned int*)(p + 256);   // 8 x 64B-strided uints
    p += 2048;
    __bf16* xfh = (__bf16*)p; p += (size_t)8388608 * 2;
    __bf16* xfl = (__bf16*)p; p += (size_t)8388608 * 2;
    __bf16* w1h = (__bf16*)p; p += (size_t)8192000 * 2;
    __bf16* w1l = (__bf16*)p; p += (size_t)8192000 * 2;
    __bf16* w2h = (__bf16*)p; p += (size_t)8192000 * 2;
    __bf16* w2l = (__bf16*)p; p += (size_t)8192000 * 2;

    // ---- preprocessing ----
    zero_ws<<<1026, 256, 0, stream>>>((unsigned int*)d_ws, 262656);
    split_x<<<4096, 256, 0, stream>>>(x, xfh, xfl);
    pack_w2<<<dim3(250, 2), 256, 0, stream>>>(W1, U1, W2, U2, w1h, w1l, w2h, w2l);

    // ---- persistent pipelined recurrence (all 129 phases) ----
    lstm_persist<<<NBLK, 256, 0, stream>>>(xfh, xfl, w1h, w1l, w2h, w2l,
                                           b1, b2, hbuf, bar, flag, xcdm, xcdd);

    // h2(127) is in buffer index 1
    out_proj<<<64, 256, 0, stream>>>(hbuf + 5 * 65536, hbuf + 7 * 65536, Wo, bo, out);
}

// Round 10
// 1436.644 us; speedup vs baseline: 1.4542x; 1.3604x over previous
//
#include <hip/hip_runtime.h>
#include <hip/hip_bf16.h>

#define TT 128
#define DD 1024   // padded per-operand K
#define HH 1000
#define NBLK 250  // persistent blocks: 125 per layer

typedef float f32x4 __attribute__((ext_vector_type(4)));
typedef __bf16 bf16x8 __attribute__((ext_vector_type(8)));

__device__ __forceinline__ bf16x8 asbf(f32x4 v) { return __builtin_bit_cast(bf16x8, v); }

// A-feed load: sc0 = L1-bypass, L2-CACHEABLE (L2 broadcasts to ~31 blocks/XCD;
// staleness cleared by ONE buffer_inv per XCD per phase — round 9 verified).
__device__ __forceinline__ void ld_a(bf16x8* d, const char* p) {
    asm volatile("global_load_dwordx4 %0, %1, off sc0" : "=v"(*d) : "v"(p));
}
// h store: sc0 sc1 = write-through to L3 (coherence point); never dirty in L2.
__device__ __forceinline__ void st_byp(char* p, bf16x8 v) {
    asm volatile("global_store_dwordx4 %0, %1, off sc0 sc1" :: "v"(p), "v"(v) : "memory");
}

#define AT_RLX __ATOMIC_RELAXED
#define SC_AGT __HIP_MEMORY_SCOPE_AGENT

// ---------------------------------------------------------------------------
__global__ void zero_ws(unsigned int* __restrict__ p, int nwords) {
    int i = blockIdx.x * blockDim.x + threadIdx.x;
    if (i < nwords) p[i] = 0u;
}

// ---------------------------------------------------------------------------
// split x into bf16 hi/lo in MFMA A-fragment order (verified):
// unit gid = ((t*32 + ks)*4 + mt)*64 + lane ; elem j = x[mt*16+(lane&15)][t][ks*32+(lane>>4)*8+j]
__global__ void split_x(const float* __restrict__ x, __bf16* __restrict__ xfh,
                        __bf16* __restrict__ xfl) {
    int gid = blockIdx.x * 256 + threadIdx.x;     // 1,048,576 units
    int lane = gid & 63;
    int mt = (gid >> 6) & 3;
    int ks = (gid >> 8) & 31;
    int t  = gid >> 13;
    int row = mt * 16 + (lane & 15);
    int k0  = ks * 32 + (lane >> 4) * 8;
    const float* sp = x + ((size_t)row * TT + t) * 1024 + k0;
    float4 v0 = *(const float4*)sp;
    float4 v1 = *(const float4*)(sp + 4);
    float f[8] = {v0.x, v0.y, v0.z, v0.w, v1.x, v1.y, v1.z, v1.w};
    bf16x8 hv, lv;
#pragma unroll
    for (int j = 0; j < 8; ++j) {
        __bf16 h = (__bf16)f[j];
        hv[j] = h;
        lv[j] = (__bf16)(f[j] - (float)h);
    }
    ((bf16x8*)xfh)[gid] = hv;
    ((bf16x8*)xfl)[gid] = lv;
}

// ---------------------------------------------------------------------------
// Pack W/U into MFMA-B-fragment order via LDS tile (verified layout):
// unit = (nt*256 + kb)*16 + col; col' = 4*cell + gate; kb<128 = W, kb>=128 = U.
__global__ __launch_bounds__(256) void pack_w2(
    const float* __restrict__ W1, const float* __restrict__ U1,
    const float* __restrict__ W2, const float* __restrict__ U2,
    __bf16* __restrict__ w1h, __bf16* __restrict__ w1l,
    __bf16* __restrict__ w2h, __bf16* __restrict__ w2l)
{
    int nt = blockIdx.x;          // 0..249
    int layer = blockIdx.y;       // 0..1
    const float* R1 = layer ? W2 : W1;
    const float* R2 = layer ? U2 : U1;
    int k1v = layer ? HH : 1024;
    __bf16* dh = layer ? w2h : w1h;
    __bf16* dl = layer ? w2l : w1l;
    int tid = threadIdx.x;

    __shared__ float lt[64][21];

    int kk = tid >> 2, g = tid & 3;           // load role: 64 k rows x 4 gates
    for (int c = 0; c < 32; ++c) {            // 64 k per iter
        int k = c * 64 + kk;
        float4 v = {0.f, 0.f, 0.f, 0.f};
        if (k < 1024) {
            if (k < k1v) v = *(const float4*)(R1 + (size_t)k * 4000 + g * 1000 + nt * 4);
        } else {
            int k2 = k - 1024;
            if (k2 < HH) v = *(const float4*)(R2 + (size_t)k2 * 4000 + g * 1000 + nt * 4);
        }
        lt[kk][g * 4 + 0] = v.x; lt[kk][g * 4 + 1] = v.y;
        lt[kk][g * 4 + 2] = v.z; lt[kk][g * 4 + 3] = v.w;
        __syncthreads();
        if (tid < 128) {
            int kbl = tid >> 4, col = tid & 15;
            int li = (col & 3) * 4 + (col >> 2);   // gate*4 + cell_local
            bf16x8 hv, lv;
#pragma unroll
            for (int j = 0; j < 8; ++j) {
                float f = lt[kbl * 8 + j][li];
                __bf16 h = (__bf16)f;
                hv[j] = h;
                lv[j] = (__bf16)(f - (float)h);
            }
            size_t unit = ((size_t)nt * 256 + c * 8 + kbl) * 16 + col;
            ((bf16x8*)dh)[unit] = hv;
            ((bf16x8*)dl)[unit] = lv;
        }
        __syncthreads();
    }
}

// ---------------------------------------------------------------------------
// Persistent LSTM. Weights in AGPRs ("+a" pin, verified r6). sc0 A-loads,
// sc0sc1 h-stores, one buffer_inv per XCD per phase (verified r9).
// NEW: hierarchical XCD-tree barrier — per-XCD arrival lines (8x parallel),
// <=8 global RMWs/phase, per-XCD release flags. Removes the 250-way
// same-line atomic serialization that was the r6-r9 ~10us/phase floor.
__global__ __launch_bounds__(256, 1) void lstm_persist(
    const __bf16* __restrict__ xfh, const __bf16* __restrict__ xfl,
    const __bf16* __restrict__ w1h, const __bf16* __restrict__ w1l,
    const __bf16* __restrict__ w2h, const __bf16* __restrict__ w2l,
    const float* __restrict__ b1, const float* __restrict__ b2,
    __bf16* hbuf, unsigned int* ctrl)
{
    // ctrl layout (uints, 64B-strided groups):
    //  [0]=bar0  [16]=flag0  [32..39]=xcdm  [48]=gArr  [64]=gFlag
    //  [128 + x*16] = xcdArr[x] ; [384 + x*16] = xcdFlag[x]
    unsigned* bar0  = ctrl + 0;
    unsigned* flag0 = ctrl + 16;
    unsigned* xcdm  = ctrl + 32;
    unsigned* gArr  = ctrl + 48;
    unsigned* gFlag = ctrl + 64;
    unsigned* xcdArr  = ctrl + 128;
    unsigned* xcdFlag = ctrl + 384;

    const int bid = blockIdx.x;
    const int layer = bid >= 125;
    const int nb = layer ? bid - 125 : bid;
    const int tid = threadIdx.x;
    const int lane = tid & 63, w = tid >> 6;
    const int op = w >> 1, kh = w & 1;
    const int ln = lane & 15, kg = lane >> 4;

    const char* h1h[2] = { (const char*)(hbuf + 0 * 65536), (const char*)(hbuf + 1 * 65536) };
    const char* h1l[2] = { (const char*)(hbuf + 2 * 65536), (const char*)(hbuf + 3 * 65536) };
    const char* h2h[2] = { (const char*)(hbuf + 4 * 65536), (const char*)(hbuf + 5 * 65536) };
    const char* h2l[2] = { (const char*)(hbuf + 6 * 65536), (const char*)(hbuf + 7 * 65536) };

    // ---- startup: register on XCD, one-time global barrier, learn counts ----
    __shared__ unsigned s_x, s_cnt, s_nx;
    if (tid == 0) {
        unsigned x;
        asm volatile("s_getreg_b32 %0, hwreg(HW_REG_XCC_ID)" : "=s"(x));
        x &= 7u;
        __hip_atomic_fetch_add(&xcdm[x], 1u, AT_RLX, SC_AGT);
        // release: xcdm increment visible before bar0 arrival
        unsigned old = __hip_atomic_fetch_add(bar0, 1u, __ATOMIC_ACQ_REL, SC_AGT);
        if (old == NBLK - 1u) {
            __hip_atomic_store(flag0, 1u, __ATOMIC_RELEASE, SC_AGT);
        } else {
            while (__hip_atomic_load(flag0, __ATOMIC_ACQUIRE, SC_AGT) < 1u)
                __builtin_amdgcn_s_sleep(1);
        }
        unsigned cnt = __hip_atomic_load(&xcdm[x], AT_RLX, SC_AGT);
        unsigned nx = 0;
        for (int i = 0; i < 8; ++i)
            nx += (__hip_atomic_load(&xcdm[i], AT_RLX, SC_AGT) > 0u) ? 1u : 0u;
        s_x = x; s_cnt = cnt; s_nx = nx;
    }

    // ---- preload weight panel into AGPRs (verified pin, round 6) ----
    const f32x4* wfh = (const f32x4*)(layer ? w2h : w1h);
    const f32x4* wfl = (const f32x4*)(layer ? w2l : w1l);
    f32x4 WH[32], WL[32];
#pragma unroll
    for (int nt2 = 0; nt2 < 2; ++nt2)
#pragma unroll
        for (int ks = 0; ks < 16; ++ks) {
            int kb = op * 128 + kh * 64 + ks * 4 + kg;
            size_t unit = ((size_t)(nb * 2 + nt2) * 256 + kb) * 16 + ln;
            WH[nt2 * 16 + ks] = wfh[unit];
            WL[nt2 * 16 + ks] = wfl[unit];
        }
#define PIN8(p0,p1,p2,p3,p4,p5,p6,p7) \
    asm volatile("" : "+a"(p0),"+a"(p1),"+a"(p2),"+a"(p3),"+a"(p4),"+a"(p5),"+a"(p6),"+a"(p7))
    PIN8(WH[0],WH[1],WH[2],WH[3],WH[4],WH[5],WH[6],WH[7]);
    PIN8(WH[8],WH[9],WH[10],WH[11],WH[12],WH[13],WH[14],WH[15]);
    PIN8(WH[16],WH[17],WH[18],WH[19],WH[20],WH[21],WH[22],WH[23]);
    PIN8(WH[24],WH[25],WH[26],WH[27],WH[28],WH[29],WH[30],WH[31]);
    PIN8(WL[0],WL[1],WL[2],WL[3],WL[4],WL[5],WL[6],WL[7]);
    PIN8(WL[8],WL[9],WL[10],WL[11],WL[12],WL[13],WL[14],WL[15]);
    PIN8(WL[16],WL[17],WL[18],WL[19],WL[20],WL[21],WL[22],WL[23]);
    PIN8(WL[24],WL[25],WL[26],WL[27],WL[28],WL[29],WL[30],WL[31]);
#undef PIN8

    // ---- per-thread bias + register-resident c state ----
    const float* bias = layer ? b2 : b1;
    float bias_q[2][4];
#pragma unroll
    for (int q = 0; q < 2; ++q) {
        int task = tid * 2 + q;
        int n = nb * 8 + (task & 7);
#pragma unroll
        for (int g = 0; g < 4; ++g) bias_q[q][g] = bias[(size_t)g * HH + n];
    }
    float creg[2] = {0.f, 0.f};

    __shared__ float zs[2][64][34];   // pad 34 -> exact 2-way (free)
    __shared__ float hs[64][9];
    __syncthreads();                  // s_x/s_cnt/s_nx visible

#pragma unroll 1
    for (int t = 0; t <= TT; ++t) {
        const bool active = layer ? (t >= 1) : (t <= TT - 1);
        if (active) {
            const char *pAh, *pAl;
            char *poh, *pol;
            if (layer == 0) {
                if (op == 0) { pAh = (const char*)xfh + (size_t)t * 131072;
                               pAl = (const char*)xfl + (size_t)t * 131072; }
                else         { pAh = h1h[(t + 1) & 1]; pAl = h1l[(t + 1) & 1]; }
                poh = (char*)h1h[t & 1]; pol = (char*)h1l[t & 1];
            } else {
                if (op == 0) { pAh = h1h[(t + 1) & 1]; pAl = h1l[(t + 1) & 1]; }
                else         { pAh = h2h[t & 1];       pAl = h2l[t & 1]; }
                poh = (char*)h2h[(t + 1) & 1]; pol = (char*)h2l[(t + 1) & 1];
            }
            pAh += ((size_t)kh * 4096 + lane) * 16;
            pAl += ((size_t)kh * 4096 + lane) * 16;

            f32x4 acc[2][4];
#pragma unroll
            for (int n2 = 0; n2 < 2; ++n2)
#pragma unroll
                for (int mt = 0; mt < 4; ++mt) acc[n2][mt] = (f32x4){0.f, 0.f, 0.f, 0.f};

            bf16x8 rh[4][4], rl[4][4];
#define LDB(s, k) do { _Pragma("unroll") \
    for (int mt = 0; mt < 4; ++mt) { \
        ld_a(&rh[s][mt], pAh + (size_t)((k) * 256 + mt * 64) * 16); \
        ld_a(&rl[s][mt], pAl + (size_t)((k) * 256 + mt * 64) * 16); \
    } } while (0)
#define CPK(k, s) do { _Pragma("unroll") \
    for (int n2 = 0; n2 < 2; ++n2) { \
        bf16x8 wh_ = asbf(WH[n2 * 16 + (k)]); \
        bf16x8 wl_ = asbf(WL[n2 * 16 + (k)]); \
        _Pragma("unroll") \
        for (int mt = 0; mt < 4; ++mt) { \
            acc[n2][mt] = __builtin_amdgcn_mfma_f32_16x16x32_bf16(rh[s][mt], wh_, acc[n2][mt], 0, 0, 0); \
            acc[n2][mt] = __builtin_amdgcn_mfma_f32_16x16x32_bf16(rh[s][mt], wl_, acc[n2][mt], 0, 0, 0); \
            acc[n2][mt] = __builtin_amdgcn_mfma_f32_16x16x32_bf16(rl[s][mt], wh_, acc[n2][mt], 0, 0, 0); \
        } } } while (0)

            LDB(0, 0); LDB(1, 1); LDB(2, 2); LDB(3, 3);
#pragma unroll
            for (int ks = 0; ks < 16; ++ks) {
                if (ks <= 12)      asm volatile("s_waitcnt vmcnt(24)" ::: "memory");
                else if (ks == 13) asm volatile("s_waitcnt vmcnt(16)" ::: "memory");
                else if (ks == 14) asm volatile("s_waitcnt vmcnt(8)"  ::: "memory");
                else               asm volatile("s_waitcnt vmcnt(0)"  ::: "memory");
                __builtin_amdgcn_sched_barrier(0);
                CPK(ks, ks & 3);
                if (ks < 12) LDB(ks & 3, ks + 4);
            }
#undef LDB
#undef CPK

            // ---- two-stage partial-z reduction: kh0 writes, kh1 adds ----
            if (kh == 0) {
#pragma unroll
                for (int n2 = 0; n2 < 2; ++n2)
#pragma unroll
                    for (int mt = 0; mt < 4; ++mt)
#pragma unroll
                        for (int r = 0; r < 4; ++r)
                            zs[op][mt * 16 + kg * 4 + r][n2 * 16 + ln] = acc[n2][mt][r];
            }
            __syncthreads();
            if (kh == 1) {
#pragma unroll
                for (int n2 = 0; n2 < 2; ++n2)
#pragma unroll
                    for (int mt = 0; mt < 4; ++mt)
#pragma unroll
                        for (int r = 0; r < 4; ++r)
                            zs[op][mt * 16 + kg * 4 + r][n2 * 16 + ln] += acc[n2][mt][r];
            }
            __syncthreads();

            // ---- fused gates: 512 (b,cell) tasks, 2/thread; c in registers ----
#pragma unroll
            for (int q = 0; q < 2; ++q) {
                int task = tid * 2 + q;
                int b = task >> 3, cl = task & 7;
                float zg[4];
#pragma unroll
                for (int g = 0; g < 4; ++g)
                    zg[g] = zs[0][b][cl * 4 + g] + zs[1][b][cl * 4 + g] + bias_q[q][g];
                float ig = 1.f / (1.f + __expf(-zg[0]));
                float fg = 1.f / (1.f + __expf(-zg[1]));
                float gg = 1.f - 2.f / (__expf(2.f * zg[2]) + 1.f);
                float og = 1.f / (1.f + __expf(-zg[3]));
                float cn = fg * creg[q] + ig * gg;
                creg[q] = cn;
                hs[b][cl] = og * (1.f - 2.f / (__expf(2.f * cn) + 1.f));
            }
            __syncthreads();

            // ---- write h in fragment order via bypass stores (-> L3) ----
            if (tid < 64) {
                int b = tid;
                int mt = b >> 4, lnn = b & 15;
                int ksx = nb >> 2, kgg = nb & 3;
                bf16x8 hv, lv;
#pragma unroll
                for (int j = 0; j < 8; ++j) {
                    float v = hs[b][j];
                    __bf16 h = (__bf16)v;
                    hv[j] = h;
                    lv[j] = (__bf16)(v - (float)h);
                }
                size_t boff = (((size_t)ksx * 4 + mt) * 64 + kgg * 16 + lnn) * 16;
                st_byp(poh + boff, hv);
                st_byp(pol + boff, lv);
            }
        }

        // ---- hierarchical XCD-tree barrier (one buffer_inv per XCD) ----
        if (t < TT) {
            asm volatile("s_waitcnt vmcnt(0)" ::: "memory");  // h stores at L3
            __syncthreads();
            if (tid == 0) {
                const unsigned x = s_x, cnt = s_cnt, nx = s_nx;
                const unsigned tp1 = (unsigned)(t + 1);
                unsigned* aP = xcdArr + x * 16;
                unsigned* fP = xcdFlag + x * 16;
                unsigned arr = __hip_atomic_fetch_add(aP, 1u, AT_RLX, SC_AGT) + 1u;
                if (arr == cnt * tp1) {
                    // last arriver on this XCD -> global stage
                    unsigned g = __hip_atomic_fetch_add(gArr, 1u, AT_RLX, SC_AGT) + 1u;
                    if (g == nx * tp1) {
                        __hip_atomic_store(gFlag, tp1, AT_RLX, SC_AGT);
                    } else {
                        while (__hip_atomic_load(gFlag, AT_RLX, SC_AGT) < tp1)
                            __builtin_amdgcn_s_sleep(1);
                    }
                    // drop stale clean h lines from this XCD's L2, then release
                    __builtin_amdgcn_fence(__ATOMIC_ACQUIRE, "agent");
                    asm volatile("s_waitcnt vmcnt(0) lgkmcnt(0)" ::: "memory");
                    __hip_atomic_store(fP, tp1, AT_RLX, SC_AGT);
                } else {
                    while (__hip_atomic_load(fP, AT_RLX, SC_AGT) < tp1)
                        __builtin_amdgcn_s_sleep(1);
                }
            }
            __syncthreads();
        }
    }
}

// ---------------------------------------------------------------------------
// out[b][o] = bo[o] + sum_n h2[b][n] * Wo[n][o] ; h2 in fragment order
__global__ void out_proj(const __bf16* __restrict__ h2h, const __bf16* __restrict__ h2l,
                         const float* __restrict__ Wo, const float* __restrict__ bo,
                         float* __restrict__ out)
{
    int b = blockIdx.x, tid = threadIdx.x;
    int mt = b >> 4, ln = b & 15;
    float acc[6] = {0, 0, 0, 0, 0, 0};
    for (int n = tid; n < HH; n += 256) {
        int ks = n >> 5, kg = (n >> 3) & 3, j = n & 7;
        size_t idx = (((size_t)ks * 4 + mt) * 64 + kg * 16 + ln) * 8 + j;
        float h = (float)h2h[idx] + (float)h2l[idx];
#pragma unroll
        for (int o = 0; o < 6; ++o) acc[o] += h * Wo[n * 6 + o];
    }
#pragma unroll
    for (int o = 0; o < 6; ++o)
        for (int off = 32; off; off >>= 1) acc[o] += __shfl_down(acc[o], off, 64);
    __shared__ float red[4][6];
    int lane = tid & 63, wv = tid >> 6;
    if (lane == 0) {
#pragma unroll
        for (int o = 0; o < 6; ++o) red[wv][o] = acc[o];
    }
    __syncthreads();
    if (tid < 6) {
        float s = bo[tid];
#pragma unroll
        for (int w = 0; w < 4; ++w) s += red[w][tid];
        out[b * 6 + tid] = s;
    }
}

// ---------------------------------------------------------------------------
extern "C" void kernel_launch(void* const* d_in, const int* in_sizes, int n_in,
                              void* d_out, int out_size, void* d_ws, size_t ws_size,
                              hipStream_t stream) {
    const float* x  = (const float*)d_in[0];
    const float* W1 = (const float*)d_in[1];
    const float* U1 = (const float*)d_in[2];
    const float* b1 = (const float*)d_in[3];
    const float* W2 = (const float*)d_in[4];
    const float* U2 = (const float*)d_in[5];
    const float* b2 = (const float*)d_in[6];
    const float* Wo = (const float*)d_in[7];
    const float* bo = (const float*)d_in[8];
    float* out = (float*)d_out;

    // ws carve: zeroed region first [hbuf 1MB, ctrl 2KB]
    char* p = (char*)d_ws;
    __bf16* hbuf = (__bf16*)p; p += (size_t)8 * 65536 * 2;     // 8 x frag[64x1024]
    unsigned int* ctrl = (unsigned int*)p; p += 2048;
    __bf16* xfh = (__bf16*)p; p += (size_t)8388608 * 2;
    __bf16* xfl = (__bf16*)p; p += (size_t)8388608 * 2;
    __bf16* w1h = (__bf16*)p; p += (size_t)8192000 * 2;
    __bf16* w1l = (__bf16*)p; p += (size_t)8192000 * 2;
    __bf16* w2h = (__bf16*)p; p += (size_t)8192000 * 2;
    __bf16* w2l = (__bf16*)p; p += (size_t)8192000 * 2;

    // ---- preprocessing ----
    zero_ws<<<1026, 256, 0, stream>>>((unsigned int*)d_ws, 262656);
    split_x<<<4096, 256, 0, stream>>>(x, xfh, xfl);
    pack_w2<<<dim3(250, 2), 256, 0, stream>>>(W1, U1, W2, U2, w1h, w1l, w2h, w2l);

    // ---- persistent pipelined recurrence (all 129 phases) ----
    lstm_persist<<<NBLK, 256, 0, stream>>>(xfh, xfl, w1h, w1l, w2h, w2l,
                                           b1, b2, hbuf, ctrl);

    // h2(127) is in buffer index 1
    out_proj<<<64, 256, 0, stream>>>(hbuf + 5 * 65536, hbuf + 7 * 65536, Wo, bo, out);
}